// Round 4
// baseline (390.996 us; speedup 1.0000x reference)
//
#include <hip/hip_runtime.h>

#define Bsz 4096
#define Tlen 512
#define IND 18
#define HD 12

typedef float v2 __attribute__((ext_vector_type(2)));

__device__ __forceinline__ v2 pkfma(v2 a, v2 b, v2 c) {
  return __builtin_elementwise_fma(a, b, c);  // -> v_pk_fma_f32
}
__device__ __forceinline__ float vsum(v2 a) { return a.x + a.y; }
__device__ __forceinline__ float sigmoid_f(float x) {
  return __builtin_amdgcn_rcpf(1.0f + __expf(-x));
}
__device__ __forceinline__ float tanh_f(float x) {
  // tanh(x) = 1 - 2/(1+exp(2x)); saturates correctly at +-inf
  return 1.0f - 2.0f * __builtin_amdgcn_rcpf(1.0f + __expf(2.0f * x));
}
// Sum over lane pairs (l, l^32): v_permlane32_swap, pure VALU, no lgkmcnt.
__device__ __forceinline__ float xor32_sum(float v) {
  unsigned int u = __float_as_uint(v);
  auto r = __builtin_amdgcn_permlane32_swap(u, u, false, false);
  return __uint_as_float(r[0]) + __uint_as_float(r[1]);
}

// 32 lanes per batch element: j = tid&15 (12 active), batch-bit = bit4,
// k-half = bit5 (reduction partner = lane^32). 2048 waves = 2 waves/SIMD.
// All dot products packed pairwise along k into v_pk_fma_f32.
// Schedule per step: [A] layer0 h-dots+gates -> h1 -> LDS write; issue h1
// readback; [B] deferred FC(t-1); [C] hh1 partials (h2_{t-1}); [D] NEXT step's
// x-partials + x reload (covers h1 LDS latency); [F] ih1 dots on fresh h1 ->
// gates -> h2 -> LDS write; [G] issue h2 readback (consumed next step at B/C).
extern "C" __global__ void __launch_bounds__(256, 2) gru2_pk(
    const float* __restrict__ x,
    const float* __restrict__ wih0, const float* __restrict__ whh0,
    const float* __restrict__ bih0, const float* __restrict__ bhh0,
    const float* __restrict__ wih1, const float* __restrict__ whh1,
    const float* __restrict__ bih1, const float* __restrict__ bhh1,
    const float* __restrict__ fcw, const float* __restrict__ fcb,
    float* __restrict__ out)
{
  const int tid    = threadIdx.x;
  const int lane15 = tid & 15;                 // gate/h index j
  const int hl     = (tid >> 5) & 1;           // k-half (partner = lane^32)
  const int g      = ((tid >> 6) << 1) | ((tid >> 4) & 1);  // batch in block (0..7)
  const int b      = blockIdx.x * 8 + g;
  const int j      = (lane15 < HD) ? lane15 : (HD - 1);
  const bool act   = (lane15 < HD);

  // per-batch LDS: [0..11]=h1, [24..35]=h2; stride 48 floats (no write aliasing)
  __shared__ float lds[8][48];
  float* sh1 = &lds[g][0];
  float* sh2 = &lds[g][24];
  const v2* sh1v = (const v2*)sh1;
  const v2* sh2v = (const v2*)sh2;

  // ---- packed per-lane weight slices (k-split by hl) ----
  v2 wrx2[4], wzx2[4], wnx2[4];  float wrxs, wzxs, wnxs;   // layer0 ih (9 = 4 pairs + 1)
#pragma unroll
  for (int i = 0; i < 4; ++i) {
    const int k = hl * 9 + 2 * i;
    wrx2[i] = (v2){ wih0[(0 * HD + j) * IND + k], wih0[(0 * HD + j) * IND + k + 1] };
    wzx2[i] = (v2){ wih0[(1 * HD + j) * IND + k], wih0[(1 * HD + j) * IND + k + 1] };
    wnx2[i] = (v2){ wih0[(2 * HD + j) * IND + k], wih0[(2 * HD + j) * IND + k + 1] };
  }
  wrxs = wih0[(0 * HD + j) * IND + hl * 9 + 8];
  wzxs = wih0[(1 * HD + j) * IND + hl * 9 + 8];
  wnxs = wih0[(2 * HD + j) * IND + hl * 9 + 8];

  v2 whr2[3], whz2[3], whn2[3];                 // layer0 hh
  v2 wr1i2[3], wz1i2[3], wn1i2[3];              // layer1 ih
  v2 wr1h2[3], wz1h2[3], wn1h2[3];              // layer1 hh
  v2 fw2[3];                                    // fc
#pragma unroll
  for (int i = 0; i < 3; ++i) {
    const int k = hl * 6 + 2 * i;
    whr2[i]  = (v2){ whh0[(0 * HD + j) * HD + k], whh0[(0 * HD + j) * HD + k + 1] };
    whz2[i]  = (v2){ whh0[(1 * HD + j) * HD + k], whh0[(1 * HD + j) * HD + k + 1] };
    whn2[i]  = (v2){ whh0[(2 * HD + j) * HD + k], whh0[(2 * HD + j) * HD + k + 1] };
    wr1i2[i] = (v2){ wih1[(0 * HD + j) * HD + k], wih1[(0 * HD + j) * HD + k + 1] };
    wz1i2[i] = (v2){ wih1[(1 * HD + j) * HD + k], wih1[(1 * HD + j) * HD + k + 1] };
    wn1i2[i] = (v2){ wih1[(2 * HD + j) * HD + k], wih1[(2 * HD + j) * HD + k + 1] };
    wr1h2[i] = (v2){ whh1[(0 * HD + j) * HD + k], whh1[(0 * HD + j) * HD + k + 1] };
    wz1h2[i] = (v2){ whh1[(1 * HD + j) * HD + k], whh1[(1 * HD + j) * HD + k + 1] };
    wn1h2[i] = (v2){ whh1[(2 * HD + j) * HD + k], whh1[(2 * HD + j) * HD + k + 1] };
    fw2[i]   = (v2){ fcw[k], fcw[k + 1] };
  }
  // biases folded into half-0 lanes only
  const float rb0  = hl ? 0.f : (bih0[j] + bhh0[j]);
  const float zb0  = hl ? 0.f : (bih0[HD + j] + bhh0[HD + j]);
  const float inb0 = hl ? 0.f : bih0[2 * HD + j];
  const float hnb0 = hl ? 0.f : bhh0[2 * HD + j];
  const float rb1  = hl ? 0.f : (bih1[j] + bhh1[j]);
  const float zb1  = hl ? 0.f : (bih1[HD + j] + bhh1[HD + j]);
  const float inb1 = hl ? 0.f : bih1[2 * HD + j];
  const float hnb1 = hl ? 0.f : bhh1[2 * HD + j];
  const float fb_l = hl ? 0.f : fcb[0];

  // ---- state ----
  v2 hv1[3], hv2[3];
#pragma unroll
  for (int i = 0; i < 3; ++i) { hv1[i] = (v2){0.f, 0.f}; hv2[i] = (v2){0.f, 0.f}; }
  float h1 = 0.f, h2 = 0.f, oE = 0.f;

  const float* xp = x + (size_t)b * Tlen * IND + hl * 9;
  float* outp = out + (size_t)b * Tlen;

  float raw[9];
#pragma unroll
  for (int i = 0; i < 9; ++i) raw[i] = xp[i];        // x[0]
  v2 Pr, Pz, Pn;
  {  // x-partials for t=0
    Pr = (v2){ rb0, 0.f }; Pz = (v2){ zb0, 0.f }; Pn = (v2){ inb0, 0.f };
#pragma unroll
    for (int i = 0; i < 4; ++i) {
      v2 xv = (v2){ raw[2 * i], raw[2 * i + 1] };
      Pr = pkfma(xv, wrx2[i], Pr); Pz = pkfma(xv, wzx2[i], Pz); Pn = pkfma(xv, wnx2[i], Pn);
    }
    Pr.x = fmaf(raw[8], wrxs, Pr.x);
    Pz.x = fmaf(raw[8], wzxs, Pz.x);
    Pn.x = fmaf(raw[8], wnxs, Pn.x);
  }
#pragma unroll
  for (int i = 0; i < 9; ++i) raw[i] = xp[IND + i];  // x[1]

#define STEP(TT, DO_STORE, IS_ODD)                                                      \
  do {                                                                                  \
    /* A: layer0 h-dots into x-partials */                                              \
    v2 ra = Pr, za = Pz, ha = (v2){ hnb0, 0.f };                                        \
    _Pragma("unroll")                                                                   \
    for (int i = 0; i < 3; ++i) {                                                       \
      ra = pkfma(hv1[i], whr2[i], ra);                                                  \
      za = pkfma(hv1[i], whz2[i], za);                                                  \
      ha = pkfma(hv1[i], whn2[i], ha);                                                  \
    }                                                                                   \
    float r0  = xor32_sum(vsum(ra));                                                    \
    float z0  = xor32_sum(vsum(za));                                                    \
    float hn0 = xor32_sum(vsum(ha));                                                    \
    float in0 = xor32_sum(vsum(Pn));                                                    \
    float r = sigmoid_f(r0), zz = sigmoid_f(z0);                                        \
    float n = tanh_f(in0 + r * hn0);                                                    \
    h1 = n + zz * (h1 - n);                                                             \
    if (hl == 0 && act) sh1[j] = h1;                                                    \
    __builtin_amdgcn_wave_barrier();                                                    \
    /* E: issue h1 readback early; consumed at F */                                     \
    v2 nh0 = sh1v[hl * 3 + 0], nh1_ = sh1v[hl * 3 + 1], nh2_ = sh1v[hl * 3 + 2];        \
    /* B: deferred FC of step TT-1 (h2_{TT-1} in regs) */                               \
    v2 oa = (v2){ fb_l, 0.f };                                                          \
    _Pragma("unroll")                                                                   \
    for (int i = 0; i < 3; ++i) oa = pkfma(hv2[i], fw2[i], oa);                         \
    float o = xor32_sum(vsum(oa));                                                      \
    if (IS_ODD) { oE = o; }                                                             \
    else if (DO_STORE) {                                                                \
      if (hl == 0 && lane15 == 0) *(v2*)(outp + (TT) - 2) = (v2){ oE, o };              \
    }                                                                                   \
    /* C: layer1 hh partials (h2_{TT-1}) */                                             \
    v2 r1a = (v2){ rb1, 0.f }, z1a = (v2){ zb1, 0.f }, h1a = (v2){ hnb1, 0.f };         \
    _Pragma("unroll")                                                                   \
    for (int i = 0; i < 3; ++i) {                                                       \
      r1a = pkfma(hv2[i], wr1h2[i], r1a);                                               \
      z1a = pkfma(hv2[i], wz1h2[i], z1a);                                               \
      h1a = pkfma(hv2[i], wn1h2[i], h1a);                                               \
    }                                                                                   \
    /* D: next step's x-partials + x reload (covers h1 LDS trip) */                     \
    Pr = (v2){ rb0, 0.f }; Pz = (v2){ zb0, 0.f }; Pn = (v2){ inb0, 0.f };               \
    _Pragma("unroll")                                                                   \
    for (int i = 0; i < 4; ++i) {                                                       \
      v2 xv = (v2){ raw[2 * i], raw[2 * i + 1] };                                       \
      Pr = pkfma(xv, wrx2[i], Pr); Pz = pkfma(xv, wzx2[i], Pz); Pn = pkfma(xv, wnx2[i], Pn); \
    }                                                                                   \
    Pr.x = fmaf(raw[8], wrxs, Pr.x);                                                    \
    Pz.x = fmaf(raw[8], wzxs, Pz.x);                                                    \
    Pn.x = fmaf(raw[8], wnxs, Pn.x);                                                    \
    if ((TT) + 2 < Tlen) {                                                              \
      const float* p = xp + (size_t)((TT) + 2) * IND;                                   \
      _Pragma("unroll")                                                                 \
      for (int i = 0; i < 9; ++i) raw[i] = p[i];                                        \
    }                                                                                   \
    /* F: layer1 ih dots on fresh h1_t */                                               \
    hv1[0] = nh0; hv1[1] = nh1_; hv1[2] = nh2_;                                         \
    v2 i1a = (v2){ inb1, 0.f };                                                         \
    _Pragma("unroll")                                                                   \
    for (int i = 0; i < 3; ++i) {                                                       \
      r1a = pkfma(hv1[i], wr1i2[i], r1a);                                               \
      z1a = pkfma(hv1[i], wz1i2[i], z1a);                                               \
      i1a = pkfma(hv1[i], wn1i2[i], i1a);                                               \
    }                                                                                   \
    float r1t = xor32_sum(vsum(r1a));                                                   \
    float z1t = xor32_sum(vsum(z1a));                                                   \
    float in1 = xor32_sum(vsum(i1a));                                                   \
    float hn1 = xor32_sum(vsum(h1a));                                                   \
    float r1 = sigmoid_f(r1t), z1 = sigmoid_f(z1t);                                     \
    float n1 = tanh_f(in1 + r1 * hn1);                                                  \
    h2 = n1 + z1 * (h2 - n1);                                                           \
    if (hl == 0 && act) sh2[j] = h2;                                                    \
    __builtin_amdgcn_wave_barrier();                                                    \
    /* G: issue h2 readback; consumed next step at B/C */                               \
    hv2[0] = sh2v[hl * 3 + 0]; hv2[1] = sh2v[hl * 3 + 1]; hv2[2] = sh2v[hl * 3 + 2];    \
  } while (0)

  STEP(0, false, false);
  STEP(1, false, true);
  for (int t = 2; t < Tlen; t += 2) {
    STEP(t, true, false);
    STEP(t + 1, false, true);
  }
#undef STEP

  // epilogue: FC for t = Tlen-1; store final pair {o[510], o[511]}
  {
    v2 oa = (v2){ fb_l, 0.f };
#pragma unroll
    for (int i = 0; i < 3; ++i) oa = pkfma(hv2[i], fw2[i], oa);
    float o = xor32_sum(vsum(oa));
    if (hl == 0 && lane15 == 0) *(v2*)(outp + Tlen - 2) = (v2){ oE, o };
  }
}

extern "C" void kernel_launch(void* const* d_in, const int* in_sizes, int n_in,
                              void* d_out, int out_size, void* d_ws, size_t ws_size,
                              hipStream_t stream) {
  (void)in_sizes; (void)n_in; (void)d_ws; (void)ws_size; (void)out_size;
  const float* x    = (const float*)d_in[0];
  const float* wih0 = (const float*)d_in[1];
  const float* whh0 = (const float*)d_in[2];
  const float* bih0 = (const float*)d_in[3];
  const float* bhh0 = (const float*)d_in[4];
  const float* wih1 = (const float*)d_in[5];
  const float* whh1 = (const float*)d_in[6];
  const float* bih1 = (const float*)d_in[7];
  const float* bhh1 = (const float*)d_in[8];
  const float* fcw  = (const float*)d_in[9];
  const float* fcb  = (const float*)d_in[10];
  float* out = (float*)d_out;

  hipLaunchKernelGGL(gru2_pk, dim3(Bsz / 8), dim3(256), 0, stream,
                     x, wih0, whh0, bih0, bhh0, wih1, whh1, bih1, bhh1, fcw, fcb, out);
}

// Round 5
// 297.801 us; speedup vs baseline: 1.3129x; 1.3129x over previous
//
#include <hip/hip_runtime.h>

#define Bsz 4096
#define Tlen 512
#define IND 18
#define HD 12

typedef float v4f __attribute__((ext_vector_type(4)));

__device__ __forceinline__ float sigmoid_f(float x) {
  return __builtin_amdgcn_rcpf(1.0f + __expf(-x));
}
__device__ __forceinline__ float tanh_f(float x) {
  // tanh(x) = 1 - 2/(1+exp(2x)); saturates correctly at +-inf
  return 1.0f - 2.0f * __builtin_amdgcn_rcpf(1.0f + __expf(2.0f * x));
}

// Producer/consumer layer pipeline.
// Block = 256 threads = 4 waves: waves 0-1 (A) run layer 0 for 8 batches;
// waves 2-3 (B) run layer 1 + FC for the same 8 batches, one step behind.
// Each batch owns 16 lanes (12 active, lane j computes output j with FULL
// dots in-lane -> zero cross-lane reduction instructions). h1 flows A->B via
// double-buffered LDS + one s_barrier per step (both types execute exactly
// 512 barriers). A covers its LDS round trip with next-step x-projections;
// B covers its h1-read latency with hh1+FC dots on register-resident h2.
// 512 blocks * 4 waves = 2048 waves = 2 waves/SIMD.
extern "C" __global__ void __launch_bounds__(256, 2) gru2_pipe(
    const float* __restrict__ x,
    const float* __restrict__ wih0, const float* __restrict__ whh0,
    const float* __restrict__ bih0, const float* __restrict__ bhh0,
    const float* __restrict__ wih1, const float* __restrict__ whh1,
    const float* __restrict__ bih1, const float* __restrict__ bhh1,
    const float* __restrict__ fcw, const float* __restrict__ fcb,
    float* __restrict__ out)
{
  const int tid    = threadIdx.x;
  const int lane15 = tid & 15;
  const int g      = (tid >> 4) & 3;     // 16-lane group within wave
  const int wid    = tid >> 6;           // wave 0..3
  const bool isA   = (wid < 2);
  const int bb     = (wid & 1) * 4 + g;  // batch within block 0..7
  const int b      = blockIdx.x * 8 + bb;
  const int j      = (lane15 < HD) ? lane15 : (HD - 1);
  const bool act   = (lane15 < HD);

  __shared__ float h1buf[2][8][16];      // double-buffered h1 (A -> B)
  __shared__ float h2buf[8][16];         // B-private broadcast slot

  if (isA) {
    // ---------------- producer: layer 0 ----------------
    float wr[IND], wz[IND], wn[IND];
#pragma unroll
    for (int k = 0; k < IND; ++k) {
      wr[k] = wih0[(0 * HD + j) * IND + k];
      wz[k] = wih0[(1 * HD + j) * IND + k];
      wn[k] = wih0[(2 * HD + j) * IND + k];
    }
    float ur[HD], uz[HD], un[HD];
#pragma unroll
    for (int k = 0; k < HD; ++k) {
      ur[k] = whh0[(0 * HD + j) * HD + k];
      uz[k] = whh0[(1 * HD + j) * HD + k];
      un[k] = whh0[(2 * HD + j) * HD + k];
    }
    const float br = bih0[j] + bhh0[j];
    const float bz = bih0[HD + j] + bhh0[HD + j];
    const float bi = bih0[2 * HD + j];
    const float bh = bhh0[2 * HD + j];

    v4f hv[3];
    hv[0] = (v4f){0.f, 0.f, 0.f, 0.f};
    hv[1] = (v4f){0.f, 0.f, 0.f, 0.f};
    hv[2] = (v4f){0.f, 0.f, 0.f, 0.f};
    float h1 = 0.f;
    const float2* xp2 = (const float2*)(x + (size_t)b * Tlen * IND);

    float xn[IND];
    float ar, az, an;
    {
#pragma unroll
      for (int i = 0; i < 9; ++i) { float2 v = xp2[i]; xn[2 * i] = v.x; xn[2 * i + 1] = v.y; }
      ar = br; az = bz; an = bi;     // x-partials for t=0
#pragma unroll
      for (int k = 0; k < IND; ++k) { ar += xn[k] * wr[k]; az += xn[k] * wz[k]; an += xn[k] * wn[k]; }
#pragma unroll
      for (int i = 0; i < 9; ++i) { float2 v = xp2[9 + i]; xn[2 * i] = v.x; xn[2 * i + 1] = v.y; }  // x_1
    }

    for (int t = 0; t < Tlen; ++t) {
      // finish step t: hh0 dots on h1_{t-1} (register-resident via readback)
      float hr = ar, hz = az, hn = bh;
#pragma unroll
      for (int k = 0; k < HD; ++k) {
        float h = hv[k >> 2][k & 3];
        hr += h * ur[k]; hz += h * uz[k]; hn += h * un[k];
      }
      float r = sigmoid_f(hr), zz = sigmoid_f(hz);
      float n = tanh_f(an + r * hn);
      h1 = n + zz * (h1 - n);
      float* sp = &h1buf[t & 1][bb][0];
      if (act) sp[j] = h1;
      // readback for next step's hh0 (LDS in-order: read sees the write)
      v4f a0 = *(const v4f*)(sp + 0);
      v4f a1 = *(const v4f*)(sp + 4);
      v4f a2 = *(const v4f*)(sp + 8);
      // next-step x-projections: covers the LDS write+read latency
      ar = br; az = bz; an = bi;
#pragma unroll
      for (int k = 0; k < IND; ++k) { ar += xn[k] * wr[k]; az += xn[k] * wz[k]; an += xn[k] * wn[k]; }
      if (t + 2 < Tlen) {  // prefetch x_{t+2}
        const float2* p = xp2 + (size_t)(t + 2) * 9;
#pragma unroll
        for (int i = 0; i < 9; ++i) { float2 v = p[i]; xn[2 * i] = v.x; xn[2 * i + 1] = v.y; }
      }
      hv[0] = a0; hv[1] = a1; hv[2] = a2;
      // h1 write must be complete before B passes the barrier
      asm volatile("s_waitcnt lgkmcnt(0)" ::: "memory");
      __builtin_amdgcn_s_barrier();
      asm volatile("" ::: "memory");
    }
  } else {
    // ---------------- consumer: layer 1 + FC ----------------
    float vr[HD], vz[HD], vn[HD], ur[HD], uz[HD], un[HD], fw[HD];
#pragma unroll
    for (int k = 0; k < HD; ++k) {
      vr[k] = wih1[(0 * HD + j) * HD + k];
      vz[k] = wih1[(1 * HD + j) * HD + k];
      vn[k] = wih1[(2 * HD + j) * HD + k];
      ur[k] = whh1[(0 * HD + j) * HD + k];
      uz[k] = whh1[(1 * HD + j) * HD + k];
      un[k] = whh1[(2 * HD + j) * HD + k];
      fw[k] = fcw[k];
    }
    const float br = bih1[j] + bhh1[j];
    const float bz = bih1[HD + j] + bhh1[HD + j];
    const float bi = bih1[2 * HD + j];
    const float bh = bhh1[2 * HD + j];
    const float fb = fcb[0];

    v4f hw[3];
    hw[0] = (v4f){0.f, 0.f, 0.f, 0.f};
    hw[1] = (v4f){0.f, 0.f, 0.f, 0.f};
    hw[2] = (v4f){0.f, 0.f, 0.f, 0.f};
    float h2 = 0.f;
    float* outp = out + (size_t)b * Tlen;

    asm volatile("" ::: "memory");
    __builtin_amdgcn_s_barrier();          // pairs with A's t=0 barrier
    asm volatile("" ::: "memory");

    // iteration t computes h2_{t-1}; FC is one more step deferred (on h2_{t-2})
    for (int t = 1; t <= Tlen; ++t) {
      const float* sp = &h1buf[(t - 1) & 1][bb][0];
      v4f a0 = *(const v4f*)(sp + 0);      // h1_{t-1}, ready (post-barrier)
      v4f a1 = *(const v4f*)(sp + 4);
      v4f a2 = *(const v4f*)(sp + 8);
      // hh1 + FC dots on hw = h2_{t-2} (covers the h1 read latency)
      float hr = br, hz = bz, hn = bh, oc = fb;
#pragma unroll
      for (int k = 0; k < HD; ++k) {
        float h = hw[k >> 2][k & 3];
        hr += h * ur[k]; hz += h * uz[k]; hn += h * un[k]; oc += h * fw[k];
      }
      if (t >= 2 && lane15 == 0) outp[t - 2] = oc;
      float g1[HD];
      g1[0] = a0.x; g1[1] = a0.y; g1[2]  = a0.z; g1[3]  = a0.w;
      g1[4] = a1.x; g1[5] = a1.y; g1[6]  = a1.z; g1[7]  = a1.w;
      g1[8] = a2.x; g1[9] = a2.y; g1[10] = a2.z; g1[11] = a2.w;
      float in1 = bi;
#pragma unroll
      for (int k = 0; k < HD; ++k) { hr += g1[k] * vr[k]; hz += g1[k] * vz[k]; in1 += g1[k] * vn[k]; }
      float r = sigmoid_f(hr), zz = sigmoid_f(hz);
      float n = tanh_f(in1 + r * hn);
      h2 = n + zz * (h2 - n);
      float* sq = &h2buf[bb][0];
      if (act) sq[j] = h2;
      hw[0] = *(const v4f*)(sq + 0);       // wave-private broadcast readback
      hw[1] = *(const v4f*)(sq + 4);
      hw[2] = *(const v4f*)(sq + 8);
      if (t < Tlen) {
        asm volatile("" ::: "memory");
        __builtin_amdgcn_s_barrier();
        asm volatile("" ::: "memory");
      }
    }
    // final FC on h2_{Tlen-1}
    float oc = fb;
#pragma unroll
    for (int k = 0; k < HD; ++k) oc += hw[k >> 2][k & 3] * fw[k];
    if (lane15 == 0) outp[Tlen - 1] = oc;
  }
}

extern "C" void kernel_launch(void* const* d_in, const int* in_sizes, int n_in,
                              void* d_out, int out_size, void* d_ws, size_t ws_size,
                              hipStream_t stream) {
  (void)in_sizes; (void)n_in; (void)d_ws; (void)ws_size; (void)out_size;
  const float* x    = (const float*)d_in[0];
  const float* wih0 = (const float*)d_in[1];
  const float* whh0 = (const float*)d_in[2];
  const float* bih0 = (const float*)d_in[3];
  const float* bhh0 = (const float*)d_in[4];
  const float* wih1 = (const float*)d_in[5];
  const float* whh1 = (const float*)d_in[6];
  const float* bih1 = (const float*)d_in[7];
  const float* bhh1 = (const float*)d_in[8];
  const float* fcw  = (const float*)d_in[9];
  const float* fcb  = (const float*)d_in[10];
  float* out = (float*)d_out;

  hipLaunchKernelGGL(gru2_pipe, dim3(Bsz / 8), dim3(256), 0, stream,
                     x, wih0, whh0, bih0, bhh0, wih1, whh1, bih1, bhh1, fcw, fcb, out);
}